// Round 4
// baseline (298.632 us; speedup 1.0000x reference)
//
#include <hip/hip_runtime.h>
#include <hip/hip_bf16.h>

#define NNODES 12288
#define NEDGES (NNODES * 32)
#define ELLCAP 128  // max degree ~60 (Binomial(E,1/N)); 128 is unreachable

typedef __attribute__((ext_vector_type(4))) float f32x4;
typedef __attribute__((ext_vector_type(8))) __bf16 bf16x8;

// ---------------- fused prep: zero deg + 3 weight transpose-casts ----------------
__global__ __launch_bounds__(256) void prep_kernel(const float* __restrict__ W1,
                                                   const float* __restrict__ W2,
                                                   const float* __restrict__ W3,
                                                   __bf16* __restrict__ W1t,
                                                   __bf16* __restrict__ W2t,
                                                   __bf16* __restrict__ W3t,
                                                   int* __restrict__ deg) {
    int i = blockIdx.x * 256 + threadIdx.x;
    if (i < NNODES) { deg[i] = 0; return; }
    int j = i - NNODES;
    if (j < 512 * 256) { W1t[(size_t)(j % 256) * 512 + j / 256] = (__bf16)W1[j]; return; }
    j -= 512 * 256;
    if (j < 256 * 128) { W2t[(size_t)(j % 128) * 256 + j / 128] = (__bf16)W2[j]; return; }
    j -= 256 * 128;
    if (j < 128 * 64) { W3t[(size_t)(j % 64) * 128 + j / 64] = (__bf16)W3[j]; return; }
}

// ---------------- ELL build: one pass, no scan ----------------
__global__ __launch_bounds__(256) void scatter_ell(const int* __restrict__ row,
                                                   const int* __restrict__ col,
                                                   const float* __restrict__ w,
                                                   int* __restrict__ deg,
                                                   int2* __restrict__ ell) {
    int e = blockIdx.x * 256 + threadIdx.x;
    int r = row[e];
    int p = atomicAdd(&deg[r], 1);
    int2 cw; cw.x = col[e]; cw.y = __float_as_int(w[e]);
    ell[(size_t)r * ELLCAP + p] = cw;
}

// ---------------- dense layer GEMM: bf16 MFMA 16x16x32 ----------------
// C[M,Nc] = act(A[M,K] @ W[K,Nc]); Wt = W^T [Nc,K] bf16; A f32 cast in-register.
// 4 waves, wave tile 32x64, block tile 128x64. Grid (M/128, Nc/64): m on
// blockIdx.x so the Nc/64 blocks sharing an A-panel differ by 96 in linear id
// (96%8==0 -> same XCD -> A served from that XCD's L2 once).
template <bool TANH, int K, bool A_F32>
__global__ __launch_bounds__(256) void gemm_mfma(const void* __restrict__ Av,
                                                 const __bf16* __restrict__ Wt,
                                                 __bf16* __restrict__ C, int Nc) {
    int wave = threadIdx.x >> 6, lane = threadIdx.x & 63;
    int lr = lane & 15;
    int kg = lane >> 4;
    int m0 = blockIdx.x * 128 + wave * 32;
    int n0 = blockIdx.y * 64;
    f32x4 acc[2][4];
#pragma unroll
    for (int mi = 0; mi < 2; mi++)
#pragma unroll
        for (int ni = 0; ni < 4; ni++) acc[mi][ni] = (f32x4){0.f, 0.f, 0.f, 0.f};
#pragma unroll
    for (int k0 = 0; k0 < K; k0 += 32) {
        bf16x8 af[2], bf[4];
#pragma unroll
        for (int mi = 0; mi < 2; mi++) {
            if (A_F32) {
                const float* ap = (const float*)Av + (size_t)(m0 + mi * 16 + lr) * K + k0 + kg * 8;
                f32x4 a0 = *(const f32x4*)ap;
                f32x4 a1 = *(const f32x4*)(ap + 4);
#pragma unroll
                for (int j = 0; j < 4; j++) { af[mi][j] = (__bf16)a0[j]; af[mi][4 + j] = (__bf16)a1[j]; }
            } else {
                af[mi] = *(const bf16x8*)((const __bf16*)Av + (size_t)(m0 + mi * 16 + lr) * K + k0 + kg * 8);
            }
        }
#pragma unroll
        for (int ni = 0; ni < 4; ni++)
            bf[ni] = *(const bf16x8*)(Wt + (size_t)(n0 + ni * 16 + lr) * K + k0 + kg * 8);
#pragma unroll
        for (int mi = 0; mi < 2; mi++)
#pragma unroll
            for (int ni = 0; ni < 4; ni++)
                acc[mi][ni] = __builtin_amdgcn_mfma_f32_16x16x32_bf16(af[mi], bf[ni], acc[mi][ni], 0, 0, 0);
    }
    // C/D layout (m89-verified): col = lane&15, row = (lane>>4)*4 + reg
#pragma unroll
    for (int mi = 0; mi < 2; mi++)
#pragma unroll
        for (int ni = 0; ni < 4; ni++) {
            int col = n0 + ni * 16 + lr;
            int rowb = m0 + mi * 16 + kg * 4;
#pragma unroll
            for (int r = 0; r < 4; r++) {
                float v = acc[mi][ni][r];
                if (TANH) v = tanhf(v);
                C[(size_t)(rowb + r) * Nc + col] = (__bf16)v;
            }
        }
}

// ---------------- SpMM from ELL, bf16 gather, f32 accumulate ----------------
template <int F, bool FINAL>
__global__ __launch_bounds__(256) void spmm_ell(const int* __restrict__ deg,
                                                const int2* __restrict__ ell,
                                                const __bf16* __restrict__ h,
                                                __bf16* __restrict__ z,
                                                float* __restrict__ zf) {
    constexpr int L = F / 8;  // lanes per row
    int r = blockIdx.x * (256 / L) + threadIdx.x / L;
    int f8 = (threadIdx.x % L) * 8;
    int d = deg[r];
    const int2* er = ell + (size_t)r * ELLCAP;
    float acc[8] = {};
#pragma unroll 8
    for (int e = 0; e < d; e++) {
        int2 cw = er[e];
        float w = __int_as_float(cw.y);
        bf16x8 hv = *(const bf16x8*)(h + (size_t)cw.x * F + f8);
#pragma unroll
        for (int j = 0; j < 8; j++) acc[j] = fmaf(w, (float)hv[j], acc[j]);
    }
    bf16x8 o;
#pragma unroll
    for (int j = 0; j < 8; j++) o[j] = (__bf16)acc[j];
    *(bf16x8*)(z + (size_t)r * F + f8) = o;
    if (FINAL) {
        f32x4 o0, o1;
#pragma unroll
        for (int j = 0; j < 4; j++) { o0[j] = acc[j]; o1[j] = acc[4 + j]; }
        __builtin_nontemporal_store(o0, (f32x4*)(zf + (size_t)r * F + f8));
        __builtin_nontemporal_store(o1, (f32x4*)(zf + (size_t)r * F + f8 + 4));
    }
}

// ---------------- adj = sigmoid(Z Z^T), Z bf16 [N,64], MFMA 16x16x32 ----------------
// Block tile 128x256, 512 thr = 8 waves (2x4 grid of 64x64 wave tiles).
__global__ __launch_bounds__(512) void zzt_sigmoid(const __bf16* __restrict__ Z,
                                                   float* __restrict__ out) {
    int wave = threadIdx.x >> 6;
    int lane = threadIdx.x & 63;
    int lr = lane & 15;
    int kg = lane >> 4;
    int r0 = blockIdx.y * 128 + (wave >> 2) * 64;
    int c0 = blockIdx.x * 256 + (wave & 3) * 64;
    bf16x8 af[4][2], bfr[4][2];
#pragma unroll
    for (int i = 0; i < 4; i++)
#pragma unroll
        for (int ks = 0; ks < 2; ks++) {
            af[i][ks]  = *(const bf16x8*)(Z + (size_t)(r0 + i * 16 + lr) * 64 + ks * 32 + kg * 8);
            bfr[i][ks] = *(const bf16x8*)(Z + (size_t)(c0 + i * 16 + lr) * 64 + ks * 32 + kg * 8);
        }
    f32x4 acc[4][4];
#pragma unroll
    for (int mi = 0; mi < 4; mi++)
#pragma unroll
        for (int ni = 0; ni < 4; ni++) acc[mi][ni] = (f32x4){0.f, 0.f, 0.f, 0.f};
#pragma unroll
    for (int mi = 0; mi < 4; mi++)
#pragma unroll
        for (int ni = 0; ni < 4; ni++) {
            acc[mi][ni] = __builtin_amdgcn_mfma_f32_16x16x32_bf16(af[mi][0], bfr[ni][0], acc[mi][ni], 0, 0, 0);
            acc[mi][ni] = __builtin_amdgcn_mfma_f32_16x16x32_bf16(af[mi][1], bfr[ni][1], acc[mi][ni], 0, 0, 0);
        }
#pragma unroll
    for (int mi = 0; mi < 4; mi++)
#pragma unroll
        for (int ni = 0; ni < 4; ni++) {
            int col = c0 + ni * 16 + lr;
            int rowb = r0 + mi * 16 + kg * 4;
#pragma unroll
            for (int r = 0; r < 4; r++) {
                float e = __expf(-acc[mi][ni][r]);
                float v = __builtin_amdgcn_rcpf(1.f + e);
                __builtin_nontemporal_store(v, out + (size_t)(rowb + r) * NNODES + col);
            }
        }
}

extern "C" void kernel_launch(void* const* d_in, const int* in_sizes, int n_in,
                              void* d_out, int out_size, void* d_ws, size_t ws_size,
                              hipStream_t stream) {
    (void)in_sizes; (void)n_in; (void)out_size; (void)ws_size;
    const float* x  = (const float*)d_in[0];
    const int* erow = (const int*)d_in[1];
    const int* ecol = (const int*)d_in[2];
    const float* ew = (const float*)d_in[3];
    const float* W1 = (const float*)d_in[4];
    const float* W2 = (const float*)d_in[5];
    const float* W3 = (const float*)d_in[6];
    float* z_igae = (float*)d_out;
    float* adj = (float*)d_out + (size_t)NNODES * 64;

    char* ws = (char*)d_ws;
    size_t off = 0;
    auto alloc = [&](size_t bytes) {
        void* p = ws + off;
        off += (bytes + 255) & ~(size_t)255;
        return p;
    };
    __bf16* W1t = (__bf16*)alloc((size_t)512 * 256 * 2);
    __bf16* W2t = (__bf16*)alloc((size_t)256 * 128 * 2);
    __bf16* W3t = (__bf16*)alloc((size_t)128 * 64 * 2);
    __bf16* h1  = (__bf16*)alloc((size_t)NNODES * 256 * 2);
    __bf16* z1  = (__bf16*)alloc((size_t)NNODES * 256 * 2);
    __bf16* h2  = (__bf16*)alloc((size_t)NNODES * 128 * 2);
    __bf16* z2  = (__bf16*)alloc((size_t)NNODES * 128 * 2);
    __bf16* h3  = (__bf16*)alloc((size_t)NNODES * 64 * 2);
    __bf16* Zb  = (__bf16*)alloc((size_t)NNODES * 64 * 2);
    int* deg    = (int*)alloc(NNODES * 4);
    int2* ell   = (int2*)alloc((size_t)NNODES * ELLCAP * 8);

    // prep (zero deg + weight casts), then ELL build
    prep_kernel<<<(NNODES + 512 * 256 + 256 * 128 + 128 * 64 + 255) / 256, 256, 0, stream>>>(
        W1, W2, W3, W1t, W2t, W3t, deg);
    scatter_ell<<<NEDGES / 256, 256, 0, stream>>>(erow, ecol, ew, deg, ell);

    // layer 1: h1 = tanh(x @ W1) (f32 A cast in-register); z1 = spmm(h1)
    gemm_mfma<true, 512, true><<<dim3(NNODES / 128, 256 / 64), 256, 0, stream>>>(x, W1t, h1, 256);
    spmm_ell<256, false><<<NNODES / 8, 256, 0, stream>>>(deg, ell, h1, z1, nullptr);
    // layer 2
    gemm_mfma<true, 256, false><<<dim3(NNODES / 128, 128 / 64), 256, 0, stream>>>(z1, W2t, h2, 128);
    spmm_ell<128, false><<<NNODES / 16, 256, 0, stream>>>(deg, ell, h2, z2, nullptr);
    // layer 3 (no tanh)
    gemm_mfma<false, 128, false><<<dim3(NNODES / 128, 64 / 64), 256, 0, stream>>>(z2, W3t, h3, 64);
    spmm_ell<64, true><<<NNODES / 32, 256, 0, stream>>>(deg, ell, h3, Zb, z_igae);
    // adjacency reconstruction
    zzt_sigmoid<<<dim3(NNODES / 256, NNODES / 128), 512, 0, stream>>>((const __bf16*)Zb, adj);
}

// Round 5
// 248.819 us; speedup vs baseline: 1.2002x; 1.2002x over previous
//
#include <hip/hip_runtime.h>
#include <hip/hip_bf16.h>

#define NNODES 12288
#define NEDGES (NNODES * 32)
#define ELLCAP 128  // max degree ~56 expected (Binomial tail); 128 unreachable

typedef __attribute__((ext_vector_type(4))) float f32x4;
typedef __attribute__((ext_vector_type(8))) __bf16 bf16x8;

// ---------------- fused prep: zero deg + 3 weight transpose-casts ----------------
__global__ __launch_bounds__(256) void prep_kernel(const float* __restrict__ W1,
                                                   const float* __restrict__ W2,
                                                   const float* __restrict__ W3,
                                                   __bf16* __restrict__ W1t,
                                                   __bf16* __restrict__ W2t,
                                                   __bf16* __restrict__ W3t,
                                                   int* __restrict__ deg) {
    int i = blockIdx.x * 256 + threadIdx.x;
    if (i < NNODES) { deg[i] = 0; return; }
    int j = i - NNODES;
    if (j < 512 * 256) { W1t[(size_t)(j % 256) * 512 + j / 256] = (__bf16)W1[j]; return; }
    j -= 512 * 256;
    if (j < 256 * 128) { W2t[(size_t)(j % 128) * 256 + j / 128] = (__bf16)W2[j]; return; }
    j -= 256 * 128;
    if (j < 128 * 64) { W3t[(size_t)(j % 64) * 128 + j / 64] = (__bf16)W3[j]; return; }
}

// ---------------- ELL build: one pass, no scan ----------------
__global__ __launch_bounds__(256) void scatter_ell(const int* __restrict__ row,
                                                   const int* __restrict__ col,
                                                   const float* __restrict__ w,
                                                   int* __restrict__ deg,
                                                   int2* __restrict__ ell) {
    int e = blockIdx.x * 256 + threadIdx.x;
    int r = row[e];
    int p = atomicAdd(&deg[r], 1);
    int2 cw; cw.x = col[e]; cw.y = __float_as_int(w[e]);
    ell[(size_t)r * ELLCAP + p] = cw;
}

// ---------------- layer-1 GEMM: bf16 MFMA 16x16x32, f32 A cast in-register ----------------
// Grid (M/128, Nc/64): m on blockIdx.x so A-panel sharers differ by 96 (%8==0 -> same XCD L2).
template <bool TANH, int K, bool A_F32>
__global__ __launch_bounds__(256) void gemm_mfma(const void* __restrict__ Av,
                                                 const __bf16* __restrict__ Wt,
                                                 __bf16* __restrict__ C, int Nc) {
    int wave = threadIdx.x >> 6, lane = threadIdx.x & 63;
    int lr = lane & 15;
    int kg = lane >> 4;
    int m0 = blockIdx.x * 128 + wave * 32;
    int n0 = blockIdx.y * 64;
    f32x4 acc[2][4];
#pragma unroll
    for (int mi = 0; mi < 2; mi++)
#pragma unroll
        for (int ni = 0; ni < 4; ni++) acc[mi][ni] = (f32x4){0.f, 0.f, 0.f, 0.f};
#pragma unroll
    for (int k0 = 0; k0 < K; k0 += 32) {
        bf16x8 af[2], bf[4];
#pragma unroll
        for (int mi = 0; mi < 2; mi++) {
            if (A_F32) {
                const float* ap = (const float*)Av + (size_t)(m0 + mi * 16 + lr) * K + k0 + kg * 8;
                f32x4 a0 = *(const f32x4*)ap;
                f32x4 a1 = *(const f32x4*)(ap + 4);
#pragma unroll
                for (int j = 0; j < 4; j++) { af[mi][j] = (__bf16)a0[j]; af[mi][4 + j] = (__bf16)a1[j]; }
            } else {
                af[mi] = *(const bf16x8*)((const __bf16*)Av + (size_t)(m0 + mi * 16 + lr) * K + k0 + kg * 8);
            }
        }
#pragma unroll
        for (int ni = 0; ni < 4; ni++)
            bf[ni] = *(const bf16x8*)(Wt + (size_t)(n0 + ni * 16 + lr) * K + k0 + kg * 8);
#pragma unroll
        for (int mi = 0; mi < 2; mi++)
#pragma unroll
            for (int ni = 0; ni < 4; ni++)
                acc[mi][ni] = __builtin_amdgcn_mfma_f32_16x16x32_bf16(af[mi], bf[ni], acc[mi][ni], 0, 0, 0);
    }
    // C/D layout (m89-verified): col = lane&15, row = (lane>>4)*4 + reg
#pragma unroll
    for (int mi = 0; mi < 2; mi++)
#pragma unroll
        for (int ni = 0; ni < 4; ni++) {
            int col = n0 + ni * 16 + lr;
            int rowb = m0 + mi * 16 + kg * 4;
#pragma unroll
            for (int r = 0; r < 4; r++) {
                float v = acc[mi][ni][r];
                if (TANH) v = tanhf(v);
                C[(size_t)(rowb + r) * Nc + col] = (__bf16)v;
            }
        }
}

// ---------------- fused: z = spmm(h_in) then h_out = act(z @ W) ----------------
// Block owns 16 rows. Phase A: ELL gather-accumulate (f32) -> bf16 tile in LDS.
// Phase B: per-wave 16x16 MFMA n-tile over K, act, direct global write.
// THREADS = 16*K/8 (one bf16x8 per thread); NW = THREADS/64 waves = Nout/16 n-tiles.
template <int K, int NOUT, bool TANH>
__global__ __launch_bounds__(16 * K / 8) void fused_spmm_gemm(const int* __restrict__ deg,
                                                              const int2* __restrict__ ell,
                                                              const __bf16* __restrict__ h_in,
                                                              const __bf16* __restrict__ Wt,
                                                              __bf16* __restrict__ h_out) {
    constexpr int L = K / 8;  // lanes per row in phase A
    __shared__ __bf16 zs[16][K + 4];  // +4 pad: uniform bank slots for b128 reads
    int tid = threadIdx.x;
    int rloc = tid / L;
    int f8 = (tid % L) * 8;
    int rglob = blockIdx.x * 16 + rloc;
    int d = deg[rglob];
    const int2* er = ell + (size_t)rglob * ELLCAP;
    float acc[8] = {};
#pragma unroll 8
    for (int e = 0; e < d; e++) {
        int2 cw = er[e];
        float w = __int_as_float(cw.y);
        bf16x8 hv = *(const bf16x8*)(h_in + (size_t)cw.x * K + f8);
#pragma unroll
        for (int j = 0; j < 8; j++) acc[j] = fmaf(w, (float)hv[j], acc[j]);
    }
    bf16x8 o;
#pragma unroll
    for (int j = 0; j < 8; j++) o[j] = (__bf16)acc[j];
    *(bf16x8*)&zs[rloc][f8] = o;
    __syncthreads();
    // phase B: wave w computes out cols [w*16, w*16+16), rows = block's 16
    int wave = tid >> 6, lane = tid & 63;
    int lr = lane & 15, kg = lane >> 4;
    f32x4 c = (f32x4){0.f, 0.f, 0.f, 0.f};
#pragma unroll
    for (int ks = 0; ks < K / 32; ks++) {
        bf16x8 a = *(const bf16x8*)&zs[lr][ks * 32 + kg * 8];
        bf16x8 b = *(const bf16x8*)(Wt + (size_t)(wave * 16 + lr) * K + ks * 32 + kg * 8);
        c = __builtin_amdgcn_mfma_f32_16x16x32_bf16(a, b, c, 0, 0, 0);
    }
#pragma unroll
    for (int r = 0; r < 4; r++) {
        float v = c[r];
        if (TANH) v = tanhf(v);
        h_out[(size_t)(blockIdx.x * 16 + kg * 4 + r) * NOUT + wave * 16 + lr] = (__bf16)v;
    }
}

// ---------------- final SpMM (F=64): writes Zb bf16 + z_igae f32 ----------------
__global__ __launch_bounds__(256) void spmm_final(const int* __restrict__ deg,
                                                  const int2* __restrict__ ell,
                                                  const __bf16* __restrict__ h,
                                                  __bf16* __restrict__ z,
                                                  float* __restrict__ zf) {
    int r = blockIdx.x * 32 + threadIdx.x / 8;
    int f8 = (threadIdx.x & 7) * 8;
    int d = deg[r];
    const int2* er = ell + (size_t)r * ELLCAP;
    float acc[8] = {};
#pragma unroll 8
    for (int e = 0; e < d; e++) {
        int2 cw = er[e];
        float w = __int_as_float(cw.y);
        bf16x8 hv = *(const bf16x8*)(h + (size_t)cw.x * 64 + f8);
#pragma unroll
        for (int j = 0; j < 8; j++) acc[j] = fmaf(w, (float)hv[j], acc[j]);
    }
    bf16x8 o;
#pragma unroll
    for (int j = 0; j < 8; j++) o[j] = (__bf16)acc[j];
    *(bf16x8*)(z + (size_t)r * 64 + f8) = o;
    f32x4 o0, o1;
#pragma unroll
    for (int j = 0; j < 4; j++) { o0[j] = acc[j]; o1[j] = acc[4 + j]; }
    *(f32x4*)(zf + (size_t)r * 64 + f8) = o0;
    *(f32x4*)(zf + (size_t)r * 64 + f8 + 4) = o1;
}

// ---------------- adj = sigmoid(Z Z^T), Z bf16 [N,64] (round-3 proven shape) ----------------
__global__ __launch_bounds__(256) void zzt_sigmoid(const __bf16* __restrict__ Z,
                                                   float* __restrict__ out) {
    int wave = threadIdx.x >> 6;
    int lane = threadIdx.x & 63;
    int lr = lane & 15;
    int kg = lane >> 4;
    int r0 = blockIdx.y * 64;
    int c0 = blockIdx.x * 256 + wave * 64;
    bf16x8 af[4][2], bfr[4][2];
#pragma unroll
    for (int i = 0; i < 4; i++)
#pragma unroll
        for (int ks = 0; ks < 2; ks++) {
            af[i][ks]  = *(const bf16x8*)(Z + (size_t)(r0 + i * 16 + lr) * 64 + ks * 32 + kg * 8);
            bfr[i][ks] = *(const bf16x8*)(Z + (size_t)(c0 + i * 16 + lr) * 64 + ks * 32 + kg * 8);
        }
    f32x4 acc[4][4];
#pragma unroll
    for (int mi = 0; mi < 4; mi++)
#pragma unroll
        for (int ni = 0; ni < 4; ni++) acc[mi][ni] = (f32x4){0.f, 0.f, 0.f, 0.f};
#pragma unroll
    for (int mi = 0; mi < 4; mi++)
#pragma unroll
        for (int ni = 0; ni < 4; ni++) {
            acc[mi][ni] = __builtin_amdgcn_mfma_f32_16x16x32_bf16(af[mi][0], bfr[ni][0], acc[mi][ni], 0, 0, 0);
            acc[mi][ni] = __builtin_amdgcn_mfma_f32_16x16x32_bf16(af[mi][1], bfr[ni][1], acc[mi][ni], 0, 0, 0);
        }
#pragma unroll
    for (int mi = 0; mi < 4; mi++)
#pragma unroll
        for (int ni = 0; ni < 4; ni++) {
            int col = c0 + ni * 16 + lr;
            int rowb = r0 + mi * 16 + kg * 4;
#pragma unroll
            for (int r = 0; r < 4; r++) {
                float e = __expf(-acc[mi][ni][r]);
                out[(size_t)(rowb + r) * NNODES + col] = __builtin_amdgcn_rcpf(1.f + e);
            }
        }
}

extern "C" void kernel_launch(void* const* d_in, const int* in_sizes, int n_in,
                              void* d_out, int out_size, void* d_ws, size_t ws_size,
                              hipStream_t stream) {
    (void)in_sizes; (void)n_in; (void)out_size; (void)ws_size;
    const float* x  = (const float*)d_in[0];
    const int* erow = (const int*)d_in[1];
    const int* ecol = (const int*)d_in[2];
    const float* ew = (const float*)d_in[3];
    const float* W1 = (const float*)d_in[4];
    const float* W2 = (const float*)d_in[5];
    const float* W3 = (const float*)d_in[6];
    float* z_igae = (float*)d_out;
    float* adj = (float*)d_out + (size_t)NNODES * 64;

    char* ws = (char*)d_ws;
    size_t off = 0;
    auto alloc = [&](size_t bytes) {
        void* p = ws + off;
        off += (bytes + 255) & ~(size_t)255;
        return p;
    };
    __bf16* W1t = (__bf16*)alloc((size_t)512 * 256 * 2);
    __bf16* W2t = (__bf16*)alloc((size_t)256 * 128 * 2);
    __bf16* W3t = (__bf16*)alloc((size_t)128 * 64 * 2);
    __bf16* h1  = (__bf16*)alloc((size_t)NNODES * 256 * 2);
    __bf16* h2  = (__bf16*)alloc((size_t)NNODES * 128 * 2);
    __bf16* h3  = (__bf16*)alloc((size_t)NNODES * 64 * 2);
    __bf16* Zb  = (__bf16*)alloc((size_t)NNODES * 64 * 2);
    int* deg    = (int*)alloc(NNODES * 4);
    int2* ell   = (int2*)alloc((size_t)NNODES * ELLCAP * 8);

    // prep (zero deg + weight casts), then ELL build
    prep_kernel<<<(NNODES + 512 * 256 + 256 * 128 + 128 * 64 + 255) / 256, 256, 0, stream>>>(
        W1, W2, W3, W1t, W2t, W3t, deg);
    scatter_ell<<<NEDGES / 256, 256, 0, stream>>>(erow, ecol, ew, deg, ell);

    // layer 1: h1 = tanh(x @ W1)  (f32 A cast in-register)
    gemm_mfma<true, 512, true><<<dim3(NNODES / 128, 256 / 64), 256, 0, stream>>>(x, W1t, h1, 256);
    // fused layer 1->2: z1 = spmm(h1); h2 = tanh(z1 @ W2)   [512 thr, 8 waves]
    fused_spmm_gemm<256, 128, true><<<NNODES / 16, 512, 0, stream>>>(deg, ell, h1, W2t, h2);
    // fused layer 2->3: z2 = spmm(h2); h3 = z2 @ W3         [256 thr, 4 waves]
    fused_spmm_gemm<128, 64, false><<<NNODES / 16, 256, 0, stream>>>(deg, ell, h2, W3t, h3);
    // final spmm: z_igae = spmm(h3) (f32 out + bf16 copy for zzt)
    spmm_final<<<NNODES / 32, 256, 0, stream>>>(deg, ell, h3, Zb, z_igae);
    // adjacency reconstruction
    zzt_sigmoid<<<dim3(NNODES / 256, NNODES / 64), 256, 0, stream>>>((const __bf16*)Zb, adj);
}